// Round 14
// baseline (61.151 us; speedup 1.0000x reference)
//
#include <hip/hip_runtime.h>
#include <math.h>

#define EDIM 128
#define HDIM 256
#define NDIM 512
#define BDIM 2
#define LN_EPS 1e-5f

// Kernel 1: LayerNorm + dual projection, 4 rows per block (1 wave per row).
__global__ __launch_bounds__(256) void k_ln_proj(
    const float* __restrict__ hptr, const float* __restrict__ gamma,
    const float* __restrict__ beta, const float* __restrict__ W1,
    const float* __restrict__ b1, float* __restrict__ a_out,
    float* __restrict__ b_out)
{
    __shared__ float hn_s[4][EDIM];
    const int tid = threadIdx.x;
    const int r = tid >> 6;            // 0..3 (row within block)
    const int lane = tid & 63;
    const int row0 = blockIdx.x * 4;
    const float2 v = *(const float2*)(hptr + (row0 + r) * EDIM + lane * 2);
    float s  = v.x + v.y;
    float ss = v.x * v.x + v.y * v.y;
    #pragma unroll
    for (int k = 32; k >= 1; k >>= 1) {
        s  += __shfl_xor(s, k, 64);
        ss += __shfl_xor(ss, k, 64);
    }
    const float mu  = s * (1.0f / EDIM);
    const float var = ss * (1.0f / EDIM) - mu * mu;
    const float rs  = rsqrtf(var + LN_EPS);
    const float2 g2 = *(const float2*)(gamma + lane * 2);
    const float2 be = *(const float2*)(beta + lane * 2);
    hn_s[r][lane * 2]     = (v.x - mu) * rs * g2.x + be.x;
    hn_s[r][lane * 2 + 1] = (v.y - mu) * rs * g2.y + be.y;
    __syncthreads();
    float sa0 = 0.f, sa1 = 0.f, sa2 = 0.f, sa3 = 0.f;
    float sb0 = 0.f, sb1 = 0.f, sb2 = 0.f, sb3 = 0.f;
    #pragma unroll 4
    for (int e = 0; e < EDIM; ++e) {
        const float wa = W1[e * HDIM + tid];            // coalesced across tid
        const float wb = W1[(EDIM + e) * HDIM + tid];
        const float h0 = hn_s[0][e], h1 = hn_s[1][e];   // LDS broadcasts
        const float h2 = hn_s[2][e], h3 = hn_s[3][e];
        sa0 = fmaf(h0, wa, sa0); sa1 = fmaf(h1, wa, sa1);
        sa2 = fmaf(h2, wa, sa2); sa3 = fmaf(h3, wa, sa3);
        sb0 = fmaf(h0, wb, sb0); sb1 = fmaf(h1, wb, sb1);
        sb2 = fmaf(h2, wb, sb2); sb3 = fmaf(h3, wb, sb3);
    }
    const float bb1 = b1[tid];
    a_out[(row0 + 0) * HDIM + tid] = sa0;
    a_out[(row0 + 1) * HDIM + tid] = sa1;
    a_out[(row0 + 2) * HDIM + tid] = sa2;
    a_out[(row0 + 3) * HDIM + tid] = sa3;
    b_out[(row0 + 0) * HDIM + tid] = sb0 + bb1;
    b_out[(row0 + 1) * HDIM + tid] = sb1 + bb1;
    b_out[(row0 + 2) * HDIM + tid] = sb2 + bb1;
    b_out[(row0 + 3) * HDIM + tid] = sb3 + bb1;
}

// Fast exact-enough GELU: z * sigmoid(1.5957691*(z + 0.044715 z^3)),
// log2(e) folded; hw v_exp_f32 + v_rcp_f32. |err| vs erf-GELU ~3e-4.
// Tails: z<<0 -> exp2->inf -> rcp->0 -> g=0; z>>0 -> exp2->0 -> g=z. No NaN.
__device__ __forceinline__ float gelu_fast(float z) {
    const float z2 = z * z;
    const float q  = fmaf(-0.10294826f, z2, -2.3022082f);
    const float e  = __builtin_amdgcn_exp2f(z * q);
    const float r  = __builtin_amdgcn_rcpf(1.0f + e);
    return z * r;
}

// Kernel 2: partial p[hh][b,i,j] = sum_{h in half hh} gelu(a+b)*w2
// 32x16 (i,j) tile x 128-wide H-half per 256-thread block; PLAIN stores to
// per-half partial buffers (no atomics, no output zeroing needed).
// LDS = (32+16)*132*4 + 512 = 25856 B -> 6 blocks/CU; grid 2048.
// This is the measured-best configuration (total 48.87 us, R7); restored
// byte-identical after 6 structural variants all regressed (R8-R13).
#define HHALF 128
#define PAD 132   // row start bank = 4r mod 32: a-reads conflict-free,
                  // b-reads 2-way (free per m136)

__global__ __launch_bounds__(256, 6) void k_pair(
    const float* __restrict__ a, const float* __restrict__ bpb,
    const float* __restrict__ w2, float* __restrict__ pout)
{
    __shared__ float a_s[32][PAD];
    __shared__ float b_s[16][PAD];
    __shared__ float w2_s[HHALF];
    const int blk = blockIdx.x;           // (((bb*16+bi)*32)+bj)*2 + hh
    const int hh = blk & 1;
    const int bj = (blk >> 1) & 31;
    const int bi = (blk >> 6) & 15;
    const int bb = blk >> 10;
    const int tid = threadIdx.x;
    const int hho = hh * HHALF;

    const float* arow = a + (bb * NDIM + bi * 32) * HDIM + hho;
    const float* brow = bpb + (bb * NDIM + bj * 16) * HDIM + hho;

    if (tid < HHALF / 4) ((float4*)w2_s)[tid] = ((const float4*)(w2 + hho))[tid];

    // stage: a = 32 rows x 32 float4, b = 16 rows x 32 float4 (1536 f4)
    #pragma unroll
    for (int idx = tid; idx < 1536; idx += 256) {
        if (idx < 1024) {
            const int r = idx >> 5, c = idx & 31;
            *(float4*)&a_s[r][c * 4] = *(const float4*)(arow + r * HDIM + c * 4);
        } else {
            const int k = idx - 1024;
            const int r = k >> 5, c = k & 31;
            *(float4*)&b_s[r][c * 4] = *(const float4*)(brow + r * HDIM + c * 4);
        }
    }
    __syncthreads();

    const int ti = tid >> 4, tj = tid & 15;
    const float* ap0 = a_s[ti];
    const float* ap1 = a_s[ti + 16];
    const float* bp  = b_s[tj];
    float acc0 = 0.f, acc1 = 0.f;

    #pragma unroll 4
    for (int h4 = 0; h4 < HHALF; h4 += 4) {
        const float4 a0 = *(const float4*)(ap0 + h4);
        const float4 a1 = *(const float4*)(ap1 + h4);
        const float4 b0 = *(const float4*)(bp + h4);
        const float4 wv = *(const float4*)(w2_s + h4);
        acc0 = fmaf(wv.x, gelu_fast(a0.x + b0.x), acc0);
        acc1 = fmaf(wv.x, gelu_fast(a1.x + b0.x), acc1);
        acc0 = fmaf(wv.y, gelu_fast(a0.y + b0.y), acc0);
        acc1 = fmaf(wv.y, gelu_fast(a1.y + b0.y), acc1);
        acc0 = fmaf(wv.z, gelu_fast(a0.z + b0.z), acc0);
        acc1 = fmaf(wv.z, gelu_fast(a1.z + b0.z), acc1);
        acc0 = fmaf(wv.w, gelu_fast(a0.w + b0.w), acc0);
        acc1 = fmaf(wv.w, gelu_fast(a1.w + b0.w), acc1);
    }

    const int i0 = bi * 32 + ti;
    const int j0 = bj * 16 + tj;
    float* ob = pout + (size_t)hh * (BDIM * NDIM * NDIM) + (bb * NDIM + i0) * NDIM + j0;
    ob[0]         = acc0;
    ob[16 * NDIM] = acc1;
}

// Kernel 3: out[i,j] = 0.5*((p0+p1)[i,j] + (p0+p1)[j,i]) + b2
// via 32x32 LDS tile transpose; one block per unordered tile pair.
__global__ __launch_bounds__(256) void k_sym(const float* __restrict__ p,
                                             float* __restrict__ out,
                                             const float* __restrict__ b2) {
    __shared__ float Ta[32][33];
    __shared__ float Tb[32][33];
    const int blk = blockIdx.x;           // b*256 + ti*16 + tj
    const int b  = blk >> 8;
    const int ti = (blk >> 4) & 15;
    const int tj = blk & 15;
    if (tj < ti) return;                  // upper triangle only (block-uniform)
    const float bias = b2[0];
    const float* p0 = p + (size_t)b * NDIM * NDIM;
    const float* p1 = p0 + (size_t)BDIM * NDIM * NDIM;
    float* base = out + (size_t)b * NDIM * NDIM;
    const int tx = threadIdx.x & 31;
    const int ty = threadIdx.x >> 5;      // 0..7
    #pragma unroll
    for (int r = ty; r < 32; r += 8) {
        const int ia = (ti * 32 + r) * NDIM + tj * 32 + tx;
        const int ib = (tj * 32 + r) * NDIM + ti * 32 + tx;
        Ta[r][tx] = p0[ia] + p1[ia];
        Tb[r][tx] = p0[ib] + p1[ib];
    }
    __syncthreads();
    #pragma unroll
    for (int r = ty; r < 32; r += 8) {
        base[(ti * 32 + r) * NDIM + tj * 32 + tx] = 0.5f * (Ta[r][tx] + Tb[tx][r]) + bias;
    }
    if (ti != tj) {
        #pragma unroll
        for (int r = ty; r < 32; r += 8) {
            base[(tj * 32 + r) * NDIM + ti * 32 + tx] = 0.5f * (Tb[r][tx] + Ta[tx][r]) + bias;
        }
    }
}

extern "C" void kernel_launch(void* const* d_in, const int* in_sizes, int n_in,
                              void* d_out, int out_size, void* d_ws, size_t ws_size,
                              hipStream_t stream) {
    const float* hptr  = (const float*)d_in[0];
    const float* gamma = (const float*)d_in[1];
    const float* beta  = (const float*)d_in[2];
    const float* W1    = (const float*)d_in[3];
    const float* b1    = (const float*)d_in[4];
    const float* w2    = (const float*)d_in[5];
    const float* b2    = (const float*)d_in[6];
    float* out = (float*)d_out;

    float* a_ws = (float*)d_ws;                          // B*N*H floats = 1 MB
    float* b_ws = a_ws + BDIM * NDIM * HDIM;             // 1 MB
    float* p_ws = b_ws + BDIM * NDIM * HDIM;             // 2 x B*N*N floats = 4 MB

    k_ln_proj<<<(BDIM * NDIM) / 4, 256, 0, stream>>>(hptr, gamma, beta, W1, b1, a_ws, b_ws);
    k_pair<<<BDIM * 16 * 32 * 2, 256, 0, stream>>>(a_ws, b_ws, w2, p_ws);
    k_sym<<<BDIM * 256, 256, 0, stream>>>(p_ws, out, b2);
}

// Round 15
// 48.756 us; speedup vs baseline: 1.2542x; 1.2542x over previous
//
#include <hip/hip_runtime.h>
#include <math.h>

#define EDIM 128
#define HDIM 256
#define NDIM 512
#define BDIM 2
#define LN_EPS 1e-5f

typedef float v2f __attribute__((ext_vector_type(2)));

// Kernel 1: LayerNorm + dual projection, 4 rows per block (1 wave per row).
__global__ __launch_bounds__(256) void k_ln_proj(
    const float* __restrict__ hptr, const float* __restrict__ gamma,
    const float* __restrict__ beta, const float* __restrict__ W1,
    const float* __restrict__ b1, float* __restrict__ a_out,
    float* __restrict__ b_out)
{
    __shared__ float hn_s[4][EDIM];
    const int tid = threadIdx.x;
    const int r = tid >> 6;            // 0..3 (row within block)
    const int lane = tid & 63;
    const int row0 = blockIdx.x * 4;
    const float2 v = *(const float2*)(hptr + (row0 + r) * EDIM + lane * 2);
    float s  = v.x + v.y;
    float ss = v.x * v.x + v.y * v.y;
    #pragma unroll
    for (int k = 32; k >= 1; k >>= 1) {
        s  += __shfl_xor(s, k, 64);
        ss += __shfl_xor(ss, k, 64);
    }
    const float mu  = s * (1.0f / EDIM);
    const float var = ss * (1.0f / EDIM) - mu * mu;
    const float rs  = rsqrtf(var + LN_EPS);
    const float2 g2 = *(const float2*)(gamma + lane * 2);
    const float2 be = *(const float2*)(beta + lane * 2);
    hn_s[r][lane * 2]     = (v.x - mu) * rs * g2.x + be.x;
    hn_s[r][lane * 2 + 1] = (v.y - mu) * rs * g2.y + be.y;
    __syncthreads();
    float sa0 = 0.f, sa1 = 0.f, sa2 = 0.f, sa3 = 0.f;
    float sb0 = 0.f, sb1 = 0.f, sb2 = 0.f, sb3 = 0.f;
    #pragma unroll 4
    for (int e = 0; e < EDIM; ++e) {
        const float wa = W1[e * HDIM + tid];            // coalesced across tid
        const float wb = W1[(EDIM + e) * HDIM + tid];
        const float h0 = hn_s[0][e], h1 = hn_s[1][e];   // LDS broadcasts
        const float h2 = hn_s[2][e], h3 = hn_s[3][e];
        sa0 = fmaf(h0, wa, sa0); sa1 = fmaf(h1, wa, sa1);
        sa2 = fmaf(h2, wa, sa2); sa3 = fmaf(h3, wa, sa3);
        sb0 = fmaf(h0, wb, sb0); sb1 = fmaf(h1, wb, sb1);
        sb2 = fmaf(h2, wb, sb2); sb3 = fmaf(h3, wb, sb3);
    }
    const float bb1 = b1[tid];
    a_out[(row0 + 0) * HDIM + tid] = sa0;
    a_out[(row0 + 1) * HDIM + tid] = sa1;
    a_out[(row0 + 2) * HDIM + tid] = sa2;
    a_out[(row0 + 3) * HDIM + tid] = sa3;
    b_out[(row0 + 0) * HDIM + tid] = sb0 + bb1;
    b_out[(row0 + 1) * HDIM + tid] = sb1 + bb1;
    b_out[(row0 + 2) * HDIM + tid] = sb2 + bb1;
    b_out[(row0 + 3) * HDIM + tid] = sb3 + bb1;
}

// Packed-pair fast GELU: z * sigmoid(1.5957691*(z + 0.044715 z^3)),
// log2(e) folded. Full-rate ops as v_pk_* (2 elems/inst); exp2/rcp scalar.
// Tails: z<<0 -> exp2->inf -> rcp->0 -> g=0; z>>0 -> exp2->0 -> g=z. No NaN.
// NOTE (R14 lesson): this v2f formulation measures ~5 us faster than the
// scalar-float equivalent (39-40 vs 44-50 us k_pair) — do not "simplify".
__device__ __forceinline__ v2f gelu2(v2f z) {
    const v2f c2 = {-0.10294826f, -0.10294826f};
    const v2f c1 = {-2.3022082f, -2.3022082f};
    const v2f z2 = z * z;
    const v2f q  = __builtin_elementwise_fma(c2, z2, c1);
    const v2f p  = z * q;
    v2f e;
    e.x = __builtin_amdgcn_exp2f(p.x);
    e.y = __builtin_amdgcn_exp2f(p.y);
    const v2f d = e + 1.0f;
    v2f r;
    r.x = __builtin_amdgcn_rcpf(d.x);
    r.y = __builtin_amdgcn_rcpf(d.y);
    return z * r;
}

// Kernel 2: partial p[hh][b,i,j] = sum_{h in half hh} gelu(a+b)*w2
// 32x16 (i,j) tile x 128-wide H-half per 256-thread block; PLAIN stores to
// per-half partial buffers (no atomics, no output zeroing needed).
// LDS = (32+16)*132*4 + 512 = 25856 B -> 6 blocks/CU; grid 2048.
// Measured-best configuration: total 48.87 us (Round 7 bench).
#define HHALF 128
#define PAD 132   // row start bank = 4r mod 32: a-reads conflict-free,
                  // b-reads 2-way (free per m136)

__global__ __launch_bounds__(256, 6) void k_pair(
    const float* __restrict__ a, const float* __restrict__ bpb,
    const float* __restrict__ w2, float* __restrict__ pout)
{
    __shared__ float a_s[32][PAD];
    __shared__ float b_s[16][PAD];
    __shared__ float w2_s[HHALF];
    const int blk = blockIdx.x;           // (((bb*16+bi)*32)+bj)*2 + hh
    const int hh = blk & 1;
    const int bj = (blk >> 1) & 31;
    const int bi = (blk >> 6) & 15;
    const int bb = blk >> 10;
    const int tid = threadIdx.x;
    const int hho = hh * HHALF;

    const float* arow = a + (bb * NDIM + bi * 32) * HDIM + hho;
    const float* brow = bpb + (bb * NDIM + bj * 16) * HDIM + hho;

    if (tid < HHALF / 4) ((float4*)w2_s)[tid] = ((const float4*)(w2 + hho))[tid];

    // stage: a = 32 rows x 32 float4, b = 16 rows x 32 float4 (1536 f4)
    #pragma unroll
    for (int idx = tid; idx < 1536; idx += 256) {
        if (idx < 1024) {
            const int r = idx >> 5, c = idx & 31;
            *(float4*)&a_s[r][c * 4] = *(const float4*)(arow + r * HDIM + c * 4);
        } else {
            const int k = idx - 1024;
            const int r = k >> 5, c = k & 31;
            *(float4*)&b_s[r][c * 4] = *(const float4*)(brow + r * HDIM + c * 4);
        }
    }
    __syncthreads();

    const int ti = tid >> 4, tj = tid & 15;
    const float* ap0 = a_s[ti];
    const float* ap1 = a_s[ti + 16];
    const float* bp  = b_s[tj];
    v2f acc0 = {0.f, 0.f}, acc1 = {0.f, 0.f};

    #pragma unroll 4
    for (int h4 = 0; h4 < HHALF; h4 += 4) {
        const float4 a0 = *(const float4*)(ap0 + h4);
        const float4 a1 = *(const float4*)(ap1 + h4);
        const float4 b0 = *(const float4*)(bp + h4);
        const float4 wv = *(const float4*)(w2_s + h4);
        const v2f alo0 = {a0.x, a0.y}, ahi0 = {a0.z, a0.w};
        const v2f alo1 = {a1.x, a1.y}, ahi1 = {a1.z, a1.w};
        const v2f blo  = {b0.x, b0.y}, bhi  = {b0.z, b0.w};
        const v2f wlo  = {wv.x, wv.y}, whi  = {wv.z, wv.w};
        acc0 = __builtin_elementwise_fma(wlo, gelu2(alo0 + blo), acc0);
        acc0 = __builtin_elementwise_fma(whi, gelu2(ahi0 + bhi), acc0);
        acc1 = __builtin_elementwise_fma(wlo, gelu2(alo1 + blo), acc1);
        acc1 = __builtin_elementwise_fma(whi, gelu2(ahi1 + bhi), acc1);
    }
    const int i0 = bi * 32 + ti;
    const int j0 = bj * 16 + tj;
    float* ob = pout + (size_t)hh * (BDIM * NDIM * NDIM) + (bb * NDIM + i0) * NDIM + j0;
    ob[0]         = acc0.x + acc0.y;
    ob[16 * NDIM] = acc1.x + acc1.y;
}

// Kernel 3: out[i,j] = 0.5*((p0+p1)[i,j] + (p0+p1)[j,i]) + b2
// via 32x32 LDS tile transpose; one block per unordered tile pair.
__global__ __launch_bounds__(256) void k_sym(const float* __restrict__ p,
                                             float* __restrict__ out,
                                             const float* __restrict__ b2) {
    __shared__ float Ta[32][33];
    __shared__ float Tb[32][33];
    const int blk = blockIdx.x;           // b*256 + ti*16 + tj
    const int b  = blk >> 8;
    const int ti = (blk >> 4) & 15;
    const int tj = blk & 15;
    if (tj < ti) return;                  // upper triangle only (block-uniform)
    const float bias = b2[0];
    const float* p0 = p + (size_t)b * NDIM * NDIM;
    const float* p1 = p0 + (size_t)BDIM * NDIM * NDIM;
    float* base = out + (size_t)b * NDIM * NDIM;
    const int tx = threadIdx.x & 31;
    const int ty = threadIdx.x >> 5;      // 0..7
    #pragma unroll
    for (int r = ty; r < 32; r += 8) {
        const int ia = (ti * 32 + r) * NDIM + tj * 32 + tx;
        const int ib = (tj * 32 + r) * NDIM + ti * 32 + tx;
        Ta[r][tx] = p0[ia] + p1[ia];
        Tb[r][tx] = p0[ib] + p1[ib];
    }
    __syncthreads();
    #pragma unroll
    for (int r = ty; r < 32; r += 8) {
        base[(ti * 32 + r) * NDIM + tj * 32 + tx] = 0.5f * (Ta[r][tx] + Tb[tx][r]) + bias;
    }
    if (ti != tj) {
        #pragma unroll
        for (int r = ty; r < 32; r += 8) {
            base[(tj * 32 + r) * NDIM + ti * 32 + tx] = 0.5f * (Tb[r][tx] + Ta[tx][r]) + bias;
        }
    }
}

extern "C" void kernel_launch(void* const* d_in, const int* in_sizes, int n_in,
                              void* d_out, int out_size, void* d_ws, size_t ws_size,
                              hipStream_t stream) {
    const float* hptr  = (const float*)d_in[0];
    const float* gamma = (const float*)d_in[1];
    const float* beta  = (const float*)d_in[2];
    const float* W1    = (const float*)d_in[3];
    const float* b1    = (const float*)d_in[4];
    const float* w2    = (const float*)d_in[5];
    const float* b2    = (const float*)d_in[6];
    float* out = (float*)d_out;

    float* a_ws = (float*)d_ws;                          // B*N*H floats = 1 MB
    float* b_ws = a_ws + BDIM * NDIM * HDIM;             // 1 MB
    float* p_ws = b_ws + BDIM * NDIM * HDIM;             // 2 x B*N*N floats = 4 MB

    k_ln_proj<<<(BDIM * NDIM) / 4, 256, 0, stream>>>(hptr, gamma, beta, W1, b1, a_ws, b_ws);
    k_pair<<<BDIM * 16 * 32 * 2, 256, 0, stream>>>(a_ws, b_ws, w2, p_ws);
    k_sym<<<BDIM * 256, 256, 0, stream>>>(p_ws, out, b2);
}